// Round 9
// baseline (588.734 us; speedup 1.0000x reference)
//
#include <hip/hip_runtime.h>
#include <hip/hip_cooperative_groups.h>

namespace cg = cooperative_groups;

typedef __attribute__((ext_vector_type(8))) short bf16x8;
typedef __attribute__((ext_vector_type(4))) float f32x4;

// ---------------- problem constants ----------------
constexpr int B_   = 32;
constexpr int CIN  = 256;
constexpr int HW   = 56 * 56;      // 3136
constexpr int BOT  = 128;
constexpr int GRW  = 32;
constexpr int COUT = CIN + GRW;    // 288
constexpr int NOUT   = B_ * COUT * HW;  // 28,901,376

// ---------------- workspace layout (float units unless noted) ----------------
// array 0 = max_x1, 1 = max|batch|, 2 = max_x2, 3 = max|x3|
constexpr int NSLOT = 32;
constexpr int SSTR  = 32;                         // 32 floats = 128 B stride
constexpr int OFF_SLOT = 16;
constexpr int OFF_W1Q  = OFF_SLOT + 4 * NSLOT * SSTR;
constexpr int OFF_B1Q  = OFF_W1Q + 256;
constexpr int OFF_BFQ  = OFF_B1Q + 256;          // 128 floats (fused: raw bf; fallback: final bfq)
constexpr int OFF_SC1  = OFF_BFQ + 128;          // 128 floats (fused: raw s_w1; fallback: s_a1*s_w1)
constexpr int OFF_SC2  = OFF_SC1 + 128;          // 32 floats  (s_w2[g])
constexpr int OFF_WQ1B = OFF_SC2 + 32;           // ushort[128*256] = 16384 floats
constexpr int OFF_W2B  = OFF_WQ1B + 16384;       // ushort[9*32*128] = 18432 floats
constexpr int OFF_END  = OFF_W2B + 18432;
constexpr size_t X2F_BYTE = (size_t)OFF_END * 4;          // fp32 x2 padded CL [b][58][64][128] (60.8 MB)
constexpr size_t X2F_FLTS = (size_t)B_ * 58 * 64 * 128;
constexpr size_t X3_BYTE  = X2F_BYTE + X2F_FLTS * 4;      // fp32 x3 [b][g][hw] (12.8 MB)

__device__ __forceinline__ void slotAtomicMax(float* ws, int a, int s, float v) {
    atomicMax((unsigned*)ws + OFF_SLOT + a * NSLOT * SSTR + s * SSTR, __float_as_uint(v));
}
__device__ __forceinline__ float slotMax(const float* ws, int a) {
    float m = 0.0f;
    #pragma unroll
    for (int s = 0; s < NSLOT; s++)
        m = fmaxf(m, ws[OFF_SLOT + a * NSLOT * SSTR + s * SSTR]);
    return m;
}
__device__ __forceinline__ float blockReduceMax256(float v) {
    #pragma unroll
    for (int o = 32; o > 0; o >>= 1) v = fmaxf(v, __shfl_down(v, o, 64));
    __shared__ float sm[4];
    if ((threadIdx.x & 63) == 0) sm[threadIdx.x >> 6] = v;
    __syncthreads();
    return fmaxf(fmaxf(sm[0], sm[1]), fmaxf(sm[2], sm[3]));
}
__device__ __forceinline__ float waveReduceMax(float v) {
    #pragma unroll
    for (int o = 32; o > 0; o >>= 1) v = fmaxf(v, __shfl_down(v, o, 64));
    return v;
}
__device__ __forceinline__ float clamp8(float r)   { return fminf(fmaxf(r, -128.0f), 127.0f); }
__device__ __forceinline__ float clampBig(float r) { return fminf(fmaxf(r, -2147483648.0f), 2147483648.0f); }
__device__ __forceinline__ unsigned short bf16u(float f) { return (unsigned short)(__float_as_uint(f) >> 16); }

// =====================================================================================
// Cooperative fused kernel (any grid size; phases stride by gridDim.x).
// __launch_bounds__(256,2): VGPR<=256 so 2 blocks/CU fit with 69.1KB LDS.
// =====================================================================================
__global__ __launch_bounds__(256, 2) void fused_kernel(
        const float4* __restrict__ batch4, const float* __restrict__ s_in_p,
        const float* __restrict__ g1, const float* __restrict__ b1p,
        const float* __restrict__ m1, const float* __restrict__ v1,
        const float* __restrict__ c1w, const float* __restrict__ g2,
        const float* __restrict__ b2, const float* __restrict__ m2,
        const float* __restrict__ v2, const float* __restrict__ c2w,
        float* __restrict__ ws, float* __restrict__ out) {
    cg::grid_group grid = cg::this_grid();
    __shared__ __align__(16) char smem[69120];
    int bid = blockIdx.x, gdim = gridDim.x;
    int t = threadIdx.x, lane = t & 63, wv = t >> 6;
    int quad = lane >> 4, l16 = lane & 15;

    // ---- phase 0: scalars, BN1 weights, x2f halo, conv1/conv2 weight quant ----
    {
        unsigned short* wq1b = (unsigned short*)(ws + OFF_WQ1B);
        unsigned short* w2b  = (unsigned short*)(ws + OFF_W2B);
        for (int vb = bid; vb < 193; vb += gdim) {
            if (vb == 0) {
                unsigned* scal = (unsigned*)ws;
                for (int s = t; s < OFF_W1Q; s += 256) scal[s] = 0u;
                int c = t;
                float s_in = *s_in_p;
                float r = 1.0f / sqrtf(v1[c] + 1e-5f);
                float w1 = __fmul_rn(g1[c], r);
                float b1 = __fsub_rn(b1p[c], __fmul_rn(m1[c], w1));
                float mx = blockReduceMax256(fabsf(w1));
                float s_bn = mx / 127.0f + 1e-8f;
                ws[OFF_W1Q + c] = __fmul_rn(clamp8(rintf(w1 / s_bn)), s_bn);
                float sb = __fmul_rn(s_in, s_bn);
                ws[OFF_B1Q + c] = __fmul_rn(clampBig(rintf(b1 / sb)), sb);
            } else if (vb <= 32) {
                int b = vb - 1;
                float4* x2f4 = (float4*)((char*)ws + X2F_BYTE);
                float4 z; z.x = z.y = z.z = z.w = 0.0f;
                for (int i = t; i < 2 * 58 * 32; i += 256) {
                    int row  = i / (58 * 32);
                    int rest = i - row * (58 * 32);
                    int slot = rest >> 5, q = rest & 31;
                    int hp = row ? 57 : 0;
                    x2f4[(((size_t)(b * 58 + hp) * 64 + slot) * 128 >> 2) + q] = z;
                }
                for (int i = t; i < 56 * 2 * 32; i += 256) {
                    int hp   = 1 + (i >> 6);
                    int rest = i & 63;
                    int slot = (rest >> 5) ? 57 : 0;
                    int q = rest & 31;
                    x2f4[(((size_t)(b * 58 + hp) * 64 + slot) * 128 >> 2) + q] = z;
                }
            } else if (vb < 33 + BOT) {
                int o = vb - 33;
                float tt = __fmul_rn(g2[o], 1.0f / sqrtf(v2[o] + 1e-5f));
                float wf = __fmul_rn(c1w[o * CIN + t], tt);
                float mx = blockReduceMax256(fabsf(wf));
                float s_w1 = mx / 127.0f + 1e-8f;
                float m = clamp8(rintf(wf / s_w1));
                wq1b[o * CIN + t] = bf16u(m);
                if (t == 0) {
                    ws[OFF_SC1 + o] = s_w1;                                    // raw s_w1
                    ws[OFF_BFQ + o] = __fsub_rn(b2[o], __fmul_rn(m2[o], tt));  // raw bf
                }
            } else {
                int g = vb - 33 - BOT;
                float mx = 0.0f;
                for (int s = t; s < BOT * 9; s += 256) mx = fmaxf(mx, fabsf(c2w[g * BOT * 9 + s]));
                mx = blockReduceMax256(mx);
                float s_w2 = mx / 127.0f + 1e-8f;
                for (int s = t; s < BOT * 9; s += 256) {
                    int c = s / 9, tap = s - c * 9;
                    float m = clamp8(rintf(c2w[g * BOT * 9 + s] / s_w2));
                    w2b[(tap * GRW + g) * BOT + c] = bf16u(m);
                }
                if (t == 0) ws[OFF_SC2 + g] = s_w2;
            }
            __syncthreads();
        }
    }
    grid.sync();

    // ---- phase 1: max of relu(bn1(batch)) and max|batch| ----
    {
        const float* w1q = ws + OFF_W1Q;
        const float* b1q = ws + OFF_B1Q;
        float mx1 = 0.0f, mxb = 0.0f;
        for (int vb = bid; vb < 512; vb += gdim) {
            int tid = vb * 256 + t;                    // 0..131071
            int row = tid >> 4;                        // b*256 + c
            int f   = tid & 15;
            int c   = row & 255;
            float w = w1q[c], b = b1q[c];
            const float4* p = batch4 + (size_t)row * 784 + f;
            #pragma unroll 7
            for (int k = 0; k < 49; k++) {
                float4 v = p[k * 16];
                float x0 = fmaxf(__fadd_rn(__fmul_rn(v.x, w), b), 0.0f);
                float x1 = fmaxf(__fadd_rn(__fmul_rn(v.y, w), b), 0.0f);
                float x2 = fmaxf(__fadd_rn(__fmul_rn(v.z, w), b), 0.0f);
                float x3 = fmaxf(__fadd_rn(__fmul_rn(v.w, w), b), 0.0f);
                mx1 = fmaxf(mx1, fmaxf(fmaxf(x0, x1), fmaxf(x2, x3)));
                mxb = fmaxf(mxb, fmaxf(fmaxf(fabsf(v.x), fabsf(v.y)), fmaxf(fabsf(v.z), fabsf(v.w))));
            }
        }
        mx1 = blockReduceMax256(mx1);
        __syncthreads();
        mxb = blockReduceMax256(mxb);
        if (t == 0) {
            int s = bid & (NSLOT - 1);
            slotAtomicMax(ws, 0, s, mx1);
            slotAtomicMax(ws, 1, s, mxb);
        }
    }
    grid.sync();

    // ---- phase 2: conv1 (fused BN+ReLU+quant on stage) -> padded CL fp32 ----
    {
        unsigned*       ls = (unsigned*)smem;                       // 128*33 u32   = 16896 B
        unsigned short* lA = (unsigned short*)(smem + 16896);       // 64*136 ush   = 17408 B
        unsigned short* lW = (unsigned short*)(smem + 34304);       // 128*136 ush  = 34816 B
        const unsigned short* wq1b = (const unsigned short*)(ws + OFF_WQ1B);
        const float* w1q = ws + OFF_W1Q;
        const float* b1q = ws + OFF_B1Q;
        const float* sw1 = ws + OFF_SC1;
        const float* bfr = ws + OFF_BFQ;
        float* x2f = (float*)((char*)ws + X2F_BYTE);
        float s_a1 = slotMax(ws, 0) / 127.0f + 1e-8f;
        int mhalf = wv & 1, nhalf = wv >> 1;
        int f = t & 15, cb = t >> 4;
        float mxph = 0.0f;
        for (int tile = bid; tile < 32 * 49; tile += gdim) {
            int b = tile / 49, hw0 = (tile % 49) * 64;
            f32x4 acc[2][4];
            #pragma unroll
            for (int i = 0; i < 2; i++)
                #pragma unroll
                for (int j = 0; j < 4; j++) acc[i][j] = (f32x4){0.f, 0.f, 0.f, 0.f};
            for (int kc = 0; kc < 256; kc += 128) {
                __syncthreads();
                #pragma unroll
                for (int j = 0; j < 8; j++) {
                    int cl = cb + j * 16;
                    int c  = kc + cl;
                    float w = w1q[c], bb = b1q[c];
                    float4 v = batch4[(size_t)(b * 256 + c) * 784 + (hw0 >> 2) + f];
                    unsigned q0 = bf16u(clamp8(rintf(fmaxf(__fadd_rn(__fmul_rn(v.x, w), bb), 0.0f) / s_a1)));
                    unsigned q1 = bf16u(clamp8(rintf(fmaxf(__fadd_rn(__fmul_rn(v.y, w), bb), 0.0f) / s_a1)));
                    unsigned q2 = bf16u(clamp8(rintf(fmaxf(__fadd_rn(__fmul_rn(v.z, w), bb), 0.0f) / s_a1)));
                    unsigned q3 = bf16u(clamp8(rintf(fmaxf(__fadd_rn(__fmul_rn(v.w, w), bb), 0.0f) / s_a1)));
                    ls[cl * 33 + f * 2]     = q0 | (q1 << 16);
                    ls[cl * 33 + f * 2 + 1] = q2 | (q3 << 16);
                }
                {   // W-stage
                    int cw = t & 7, oi = t >> 3;
                    #pragma unroll
                    for (int r = 0; r < 4; r++) {
                        int o = oi + r * 32;
                        uint4 p0 = *(const uint4*)(wq1b + o * 256 + kc + cw * 16);
                        uint4 p1 = *(const uint4*)(wq1b + o * 256 + kc + cw * 16 + 8);
                        *(uint4*)&lW[o * 136 + cw * 16] = p0;
                        *(uint4*)&lW[o * 136 + cw * 16 + 8] = p1;
                    }
                }
                __syncthreads();
                #pragma unroll
                for (int k = 0; k < 4; k++) {
                    int task = t + k * 256;
                    int hw = task & 63, c8 = task >> 6;
                    int base = (hw >> 2) * 2 + ((hw >> 1) & 1);
                    int sh = (hw & 1) * 16;
                    unsigned v0 = ls[(c8 * 8 + 0) * 33 + base] >> sh;
                    unsigned v1 = ls[(c8 * 8 + 1) * 33 + base] >> sh;
                    unsigned v2 = ls[(c8 * 8 + 2) * 33 + base] >> sh;
                    unsigned v3 = ls[(c8 * 8 + 3) * 33 + base] >> sh;
                    unsigned v4 = ls[(c8 * 8 + 4) * 33 + base] >> sh;
                    unsigned v5 = ls[(c8 * 8 + 5) * 33 + base] >> sh;
                    unsigned v6 = ls[(c8 * 8 + 6) * 33 + base] >> sh;
                    unsigned v7 = ls[(c8 * 8 + 7) * 33 + base] >> sh;
                    uint4 pk;
                    pk.x = (v0 & 0xffffu) | (v1 << 16);
                    pk.y = (v2 & 0xffffu) | (v3 << 16);
                    pk.z = (v4 & 0xffffu) | (v5 << 16);
                    pk.w = (v6 & 0xffffu) | (v7 << 16);
                    *(uint4*)&lA[hw * 136 + c8 * 8] = pk;
                }
                __syncthreads();
                #pragma unroll
                for (int ks = 0; ks < 4; ks++) {
                    bf16x8 a0 = *(const bf16x8*)&lA[(mhalf * 32 + l16) * 136 + ks * 32 + quad * 8];
                    bf16x8 a1 = *(const bf16x8*)&lA[(mhalf * 32 + 16 + l16) * 136 + ks * 32 + quad * 8];
                    #pragma unroll
                    for (int nt = 0; nt < 4; nt++) {
                        bf16x8 bw = *(const bf16x8*)&lW[(nhalf * 64 + nt * 16 + l16) * 136 + ks * 32 + quad * 8];
                        acc[0][nt] = __builtin_amdgcn_mfma_f32_16x16x32_bf16(a0, bw, acc[0][nt], 0, 0, 0);
                        acc[1][nt] = __builtin_amdgcn_mfma_f32_16x16x32_bf16(a1, bw, acc[1][nt], 0, 0, 0);
                    }
                }
            }
            #pragma unroll
            for (int mt = 0; mt < 2; mt++) {
                int hwg = hw0 + mhalf * 32 + mt * 16 + quad * 4;
                int h = (int)(((unsigned)hwg * 9363u) >> 19);      // exact /56 for 0..3135
                int w = hwg - h * 56;
                float* base0 = x2f + ((size_t)(b * 58 + h + 1) * 64 + (w + 1)) * 128;
                #pragma unroll
                for (int nt = 0; nt < 4; nt++) {
                    int o = nhalf * 64 + nt * 16 + l16;
                    float s  = __fmul_rn(s_a1, sw1[o]);
                    float bb = __fmul_rn(clampBig(rintf(bfr[o] / s)), s);
                    float v0 = fmaxf(__fadd_rn(__fmul_rn(acc[mt][nt][0], s), bb), 0.0f);
                    float v1 = fmaxf(__fadd_rn(__fmul_rn(acc[mt][nt][1], s), bb), 0.0f);
                    float v2 = fmaxf(__fadd_rn(__fmul_rn(acc[mt][nt][2], s), bb), 0.0f);
                    float v3 = fmaxf(__fadd_rn(__fmul_rn(acc[mt][nt][3], s), bb), 0.0f);
                    mxph = fmaxf(mxph, fmaxf(fmaxf(v0, v1), fmaxf(v2, v3)));
                    base0[o]       = v0;
                    base0[o + 128] = v1;
                    base0[o + 256] = v2;
                    base0[o + 384] = v3;
                }
            }
        }
        float m = blockReduceMax256(mxph);
        if (t == 0) slotAtomicMax(ws, 2, bid & (NSLOT - 1), m);
    }
    grid.sync();

    // ---- phase 3: conv2 3x3 (quantize-on-stage to LDS, MFMA from LDS) ----
    {
        unsigned short* xt = (unsigned short*)smem;                 // 4*58*40 ush = 18560 B
        unsigned short* wt = (unsigned short*)(smem + 18560);       // 9*32*40 ush = 23040 B
        const float* x2f = (const float*)((char*)ws + X2F_BYTE);
        const unsigned short* w2b = (const unsigned short*)(ws + OFF_W2B);
        const float* sc2 = ws + OFF_SC2;
        float* x3 = (float*)((char*)ws + X3_BYTE);
        float s_a2 = slotMax(ws, 2) / 127.0f + 1e-8f;
        float rinv = 1.0f / s_a2;
        int r = wv >> 1;
        int wq = wv & 1;
        int w0 = wq * 24;
        float mxph = 0.0f;
        for (int tile = bid; tile < 32 * 28; tile += gdim) {
            int b = tile / 28, hg = tile % 28;
            int h = hg * 2 + r;
            const float* src = x2f + (size_t)(b * 58 + hg * 2) * 64 * 128;
            f32x4 acc[2][2];
            #pragma unroll
            for (int i = 0; i < 2; i++) { acc[i][0] = (f32x4){0.f,0.f,0.f,0.f}; acc[i][1] = (f32x4){0.f,0.f,0.f,0.f}; }
            for (int cs = 0; cs < 4; cs++) {
                __syncthreads();
                for (int s = t; s < 1152; s += 256) {
                    int gi = s >> 2, q = s & 3;
                    *(uint4*)&wt[gi * 40 + q * 8] = *(const uint4*)(w2b + gi * 128 + cs * 32 + q * 8);
                }
                #pragma unroll
                for (int k = 0; k < 8; k++) {
                    int idx = t + k * 256;
                    if (idx < 1856) {
                        int row = idx / 464;
                        int rem = idx - row * 464;
                        int slot = rem >> 3, c4 = rem & 7;
                        f32x4 v = *(const f32x4*)(src + (size_t)(row * 64 + slot) * 128 + cs * 32 + c4 * 4);
                        unsigned q0 = bf16u(clamp8(rintf(v[0] * rinv)));
                        unsigned q1 = bf16u(clamp8(rintf(v[1] * rinv)));
                        unsigned q2 = bf16u(clamp8(rintf(v[2] * rinv)));
                        unsigned q3 = bf16u(clamp8(rintf(v[3] * rinv)));
                        uint2 pk; pk.x = q0 | (q1 << 16); pk.y = q2 | (q3 << 16);
                        *(uint2*)&xt[(row * 58 + slot) * 40 + c4 * 4] = pk;
                    }
                }
                __syncthreads();
                #pragma unroll
                for (int tap = 0; tap < 9; tap++) {
                    int dh = tap / 3, dw = tap % 3;
                    bf16x8 b0 = *(const bf16x8*)&wt[(tap * 32 + l16) * 40 + quad * 8];
                    bf16x8 b1 = *(const bf16x8*)&wt[(tap * 32 + 16 + l16) * 40 + quad * 8];
                    #pragma unroll
                    for (int mt = 0; mt < 2; mt++) {
                        int slot = w0 + mt * 16 + l16 + dw;
                        bf16x8 a = *(const bf16x8*)&xt[((r + dh) * 58 + slot) * 40 + quad * 8];
                        acc[mt][0] = __builtin_amdgcn_mfma_f32_16x16x32_bf16(a, b0, acc[mt][0], 0, 0, 0);
                        acc[mt][1] = __builtin_amdgcn_mfma_f32_16x16x32_bf16(a, b1, acc[mt][1], 0, 0, 0);
                    }
                }
            }
            #pragma unroll
            for (int nt = 0; nt < 2; nt++) {
                int g = nt * 16 + l16;
                float s2 = __fmul_rn(s_a2, sc2[g]);
                #pragma unroll
                for (int mt = 0; mt < 2; mt++) {
                    int wb = w0 + mt * 16 + quad * 4;
                    if (wq == 0 || wb >= 32) {
                        float4 v;
                        v.x = __fmul_rn(acc[mt][nt][0], s2);
                        v.y = __fmul_rn(acc[mt][nt][1], s2);
                        v.z = __fmul_rn(acc[mt][nt][2], s2);
                        v.w = __fmul_rn(acc[mt][nt][3], s2);
                        mxph = fmaxf(mxph, fmaxf(fmaxf(fabsf(v.x), fabsf(v.y)), fmaxf(fabsf(v.z), fabsf(v.w))));
                        *(float4*)&x3[(size_t)(b * GRW + g) * HW + h * 56 + wb] = v;
                    }
                }
            }
        }
        float m = blockReduceMax256(mxph);
        if (t == 0) slotAtomicMax(ws, 3, bid & (NSLOT - 1), m);
    }
    grid.sync();

    // ---- phase 4: output concat + fake-quant ----
    {
        const float4* x34 = (const float4*)((const char*)ws + X3_BYTE);
        float maxb = slotMax(ws, 1);
        float max3 = slotMax(ws, 3);
        float s_out = fmaxf(maxb, max3) / 127.0f + 1e-8f;
        float4* out4 = (float4*)out;
        int n4 = NOUT / 4;
        for (int i = bid * 256 + t; i < n4; i += gdim * 256) {
            int chl = i / 784;
            int b = chl / COUT;
            int ch = chl - b * COUT;
            int hw4 = i - chl * 784;
            float4 v;
            if (ch < CIN) v = batch4[(b * CIN + ch) * 784 + hw4];
            else          v = x34[(b * GRW + (ch - CIN)) * 784 + hw4];
            float4 rr;
            rr.x = __fmul_rn(clamp8(rintf(v.x / s_out)), s_out);
            rr.y = __fmul_rn(clamp8(rintf(v.y / s_out)), s_out);
            rr.z = __fmul_rn(clamp8(rintf(v.z / s_out)), s_out);
            rr.w = __fmul_rn(clamp8(rintf(v.w / s_out)), s_out);
            out4[i] = rr;
        }
        if (bid == 0 && t == 0) out[NOUT] = s_out;
    }
}

// =====================================================================================
// Fallback path: R7's proven multi-kernel pipeline (passed @346us).
// =====================================================================================
__global__ __launch_bounds__(256) void prep_kernel(const float* __restrict__ g1, const float* __restrict__ b1p,
                                                   const float* __restrict__ m1, const float* __restrict__ v1,
                                                   const float* __restrict__ s_in_p, float* __restrict__ ws) {
    int t = threadIdx.x;
    if (blockIdx.x == 0) {
        int c = t;
        unsigned* scal = (unsigned*)ws;
        for (int s = c; s < OFF_W1Q; s += 256) scal[s] = 0u;
        float s_in = *s_in_p;
        float r = 1.0f / sqrtf(v1[c] + 1e-5f);
        float w1 = __fmul_rn(g1[c], r);
        float b1 = __fsub_rn(b1p[c], __fmul_rn(m1[c], w1));
        float mx = blockReduceMax256(fabsf(w1));
        float s_bn = mx / 127.0f + 1e-8f;
        ws[OFF_W1Q + c] = __fmul_rn(clamp8(rintf(w1 / s_bn)), s_bn);
        float sb = __fmul_rn(s_in, s_bn);
        ws[OFF_B1Q + c] = __fmul_rn(clampBig(rintf(b1 / sb)), sb);
        return;
    }
    int b = blockIdx.x - 1;
    float4* x2f4 = (float4*)((char*)ws + X2F_BYTE);
    float4 z; z.x = z.y = z.z = z.w = 0.0f;
    for (int i = t; i < 2 * 58 * 32; i += 256) {
        int row  = i / (58 * 32);
        int rest = i - row * (58 * 32);
        int slot = rest >> 5, q = rest & 31;
        int hp = row ? 57 : 0;
        x2f4[(((size_t)(b * 58 + hp) * 64 + slot) * 128 >> 2) + q] = z;
    }
    for (int i = t; i < 56 * 2 * 32; i += 256) {
        int hp   = 1 + (i >> 6);
        int rest = i & 63;
        int slot = (rest >> 5) ? 57 : 0;
        int q = rest & 31;
        x2f4[(((size_t)(b * 58 + hp) * 64 + slot) * 128 >> 2) + q] = z;
    }
}

__global__ __launch_bounds__(256) void max1_kernel(const float4* __restrict__ batch4,
                                                   float* __restrict__ ws) {
    const float* w1q = ws + OFF_W1Q;
    const float* b1q = ws + OFF_B1Q;
    int tid = blockIdx.x * 256 + threadIdx.x;
    int row = tid >> 4;
    int f   = tid & 15;
    int c   = row & 255;
    float w = w1q[c], b = b1q[c];
    const float4* p = batch4 + (size_t)row * 784 + f;
    float mx1 = 0.0f, mxb = 0.0f;
    #pragma unroll 7
    for (int k = 0; k < 49; k++) {
        float4 v = p[k * 16];
        float x0 = fmaxf(__fadd_rn(__fmul_rn(v.x, w), b), 0.0f);
        float x1 = fmaxf(__fadd_rn(__fmul_rn(v.y, w), b), 0.0f);
        float x2 = fmaxf(__fadd_rn(__fmul_rn(v.z, w), b), 0.0f);
        float x3 = fmaxf(__fadd_rn(__fmul_rn(v.w, w), b), 0.0f);
        mx1 = fmaxf(mx1, fmaxf(fmaxf(x0, x1), fmaxf(x2, x3)));
        mxb = fmaxf(mxb, fmaxf(fmaxf(fabsf(v.x), fabsf(v.y)), fmaxf(fabsf(v.z), fabsf(v.w))));
    }
    mx1 = blockReduceMax256(mx1);
    __syncthreads();
    mxb = blockReduceMax256(mxb);
    if (threadIdx.x == 0) {
        int s = blockIdx.x & (NSLOT - 1);
        slotAtomicMax(ws, 0, s, mx1);
        slotAtomicMax(ws, 1, s, mxb);
    }
}

__global__ void prep2_kernel(const float* __restrict__ c1w,
                             const float* __restrict__ g2, const float* __restrict__ b2,
                             const float* __restrict__ m2, const float* __restrict__ v2,
                             const float* __restrict__ c2w, float* __restrict__ ws) {
    int bi = blockIdx.x;
    int t = threadIdx.x;
    unsigned short* wq1b = (unsigned short*)(ws + OFF_WQ1B);
    unsigned short* w2b  = (unsigned short*)(ws + OFF_W2B);
    if (bi < BOT) {
        int o = bi;
        float tt = __fmul_rn(g2[o], 1.0f / sqrtf(v2[o] + 1e-5f));
        float wf = __fmul_rn(c1w[o * CIN + t], tt);
        float mx = blockReduceMax256(fabsf(wf));
        float s_w1 = mx / 127.0f + 1e-8f;
        float m = clamp8(rintf(wf / s_w1));
        wq1b[o * CIN + t] = bf16u(m);
        if (t == 0) {
            float s_a1 = slotMax(ws, 0) / 127.0f + 1e-8f;
            ws[OFF_SC1 + o] = __fmul_rn(s_a1, s_w1);
            float bf = __fsub_rn(b2[o], __fmul_rn(m2[o], tt));
            float sb = __fmul_rn(s_a1, s_w1);
            ws[OFF_BFQ + o] = __fmul_rn(clampBig(rintf(bf / sb)), sb);
        }
    } else {
        int g = bi - BOT;
        float mx = 0.0f;
        for (int s = t; s < BOT * 9; s += 256) mx = fmaxf(mx, fabsf(c2w[g * BOT * 9 + s]));
        mx = blockReduceMax256(mx);
        float s_w2 = mx / 127.0f + 1e-8f;
        for (int s = t; s < BOT * 9; s += 256) {
            int c = s / 9, tap = s - c * 9;
            float m = clamp8(rintf(c2w[g * BOT * 9 + s] / s_w2));
            w2b[(tap * GRW + g) * BOT + c] = bf16u(m);
        }
        if (t == 0) ws[OFF_SC2 + g] = s_w2;
    }
}

__global__ __launch_bounds__(256) void conv1_kernel(const float4* __restrict__ batch4,
                                                    float* __restrict__ ws) {
    __shared__ unsigned ls[128 * 33];
    __shared__ unsigned short lA[64 * 136];
    __shared__ unsigned short lW[128 * 136];
    __shared__ float wred[4];
    const unsigned short* wq1b = (const unsigned short*)(ws + OFF_WQ1B);
    const float* w1q = ws + OFF_W1Q;
    const float* b1q = ws + OFF_B1Q;
    const float* sc1 = ws + OFF_SC1;
    const float* bfq = ws + OFF_BFQ;
    float* x2f = (float*)((char*)ws + X2F_BYTE);
    float s_a1 = slotMax(ws, 0) / 127.0f + 1e-8f;
    int b = blockIdx.x / 49, hw0 = (blockIdx.x % 49) * 64;
    int t = threadIdx.x, lane = t & 63, wv = t >> 6;
    int quad = lane >> 4, l16 = lane & 15;
    int mhalf = wv & 1, nhalf = wv >> 1;
    int f = t & 15, cb = t >> 4;
    f32x4 acc[2][4];
    #pragma unroll
    for (int i = 0; i < 2; i++)
        #pragma unroll
        for (int j = 0; j < 4; j++) acc[i][j] = (f32x4){0.f, 0.f, 0.f, 0.f};

    for (int kc = 0; kc < 256; kc += 128) {
        __syncthreads();
        #pragma unroll
        for (int j = 0; j < 8; j++) {
            int cl = cb + j * 16;
            int c  = kc + cl;
            float w = w1q[c], bb = b1q[c];
            float4 v = batch4[(size_t)(b * 256 + c) * 784 + (hw0 >> 2) + f];
            unsigned q0 = bf16u(clamp8(rintf(fmaxf(__fadd_rn(__fmul_rn(v.x, w), bb), 0.0f) / s_a1)));
            unsigned q1 = bf16u(clamp8(rintf(fmaxf(__fadd_rn(__fmul_rn(v.y, w), bb), 0.0f) / s_a1)));
            unsigned q2 = bf16u(clamp8(rintf(fmaxf(__fadd_rn(__fmul_rn(v.z, w), bb), 0.0f) / s_a1)));
            unsigned q3 = bf16u(clamp8(rintf(fmaxf(__fadd_rn(__fmul_rn(v.w, w), bb), 0.0f) / s_a1)));
            ls[cl * 33 + f * 2]     = q0 | (q1 << 16);
            ls[cl * 33 + f * 2 + 1] = q2 | (q3 << 16);
        }
        {
            int cw = t & 7, oi = t >> 3;
            #pragma unroll
            for (int r = 0; r < 4; r++) {
                int o = oi + r * 32;
                uint4 p0 = *(const uint4*)(wq1b + o * 256 + kc + cw * 16);
                uint4 p1 = *(const uint4*)(wq1b + o * 256 + kc + cw * 16 + 8);
                *(uint4*)&lW[o * 136 + cw * 16] = p0;
                *(uint4*)&lW[o * 136 + cw * 16 + 8] = p1;
            }
        }
        __syncthreads();
        #pragma unroll
        for (int k = 0; k < 4; k++) {
            int task = t + k * 256;
            int hw = task & 63, c8 = task >> 6;
            int base = (hw >> 2) * 2 + ((hw >> 1) & 1);
            int sh = (hw & 1) * 16;
            unsigned v0 = ls[(c8 * 8 + 0) * 33 + base] >> sh;
            unsigned v1 = ls[(c8 * 8 + 1) * 33 + base] >> sh;
            unsigned v2 = ls[(c8 * 8 + 2) * 33 + base] >> sh;
            unsigned v3 = ls[(c8 * 8 + 3) * 33 + base] >> sh;
            unsigned v4 = ls[(c8 * 8 + 4) * 33 + base] >> sh;
            unsigned v5 = ls[(c8 * 8 + 5) * 33 + base] >> sh;
            unsigned v6 = ls[(c8 * 8 + 6) * 33 + base] >> sh;
            unsigned v7 = ls[(c8 * 8 + 7) * 33 + base] >> sh;
            uint4 pk;
            pk.x = (v0 & 0xffffu) | (v1 << 16);
            pk.y = (v2 & 0xffffu) | (v3 << 16);
            pk.z = (v4 & 0xffffu) | (v5 << 16);
            pk.w = (v6 & 0xffffu) | (v7 << 16);
            *(uint4*)&lA[hw * 136 + c8 * 8] = pk;
        }
        __syncthreads();
        #pragma unroll
        for (int ks = 0; ks < 4; ks++) {
            bf16x8 a0 = *(const bf16x8*)&lA[(mhalf * 32 + l16) * 136 + ks * 32 + quad * 8];
            bf16x8 a1 = *(const bf16x8*)&lA[(mhalf * 32 + 16 + l16) * 136 + ks * 32 + quad * 8];
            #pragma unroll
            for (int nt = 0; nt < 4; nt++) {
                bf16x8 bw = *(const bf16x8*)&lW[(nhalf * 64 + nt * 16 + l16) * 136 + ks * 32 + quad * 8];
                acc[0][nt] = __builtin_amdgcn_mfma_f32_16x16x32_bf16(a0, bw, acc[0][nt], 0, 0, 0);
                acc[1][nt] = __builtin_amdgcn_mfma_f32_16x16x32_bf16(a1, bw, acc[1][nt], 0, 0, 0);
            }
        }
    }
    float mx = 0.0f;
    #pragma unroll
    for (int mt = 0; mt < 2; mt++) {
        int hwg = hw0 + mhalf * 32 + mt * 16 + quad * 4;
        int h = (int)(((unsigned)hwg * 9363u) >> 19);
        int w = hwg - h * 56;
        float* base0 = x2f + ((size_t)(b * 58 + h + 1) * 64 + (w + 1)) * 128;
        #pragma unroll
        for (int nt = 0; nt < 4; nt++) {
            int o = nhalf * 64 + nt * 16 + l16;
            float s = sc1[o], bb = bfq[o];
            float v0 = fmaxf(__fadd_rn(__fmul_rn(acc[mt][nt][0], s), bb), 0.0f);
            float v1 = fmaxf(__fadd_rn(__fmul_rn(acc[mt][nt][1], s), bb), 0.0f);
            float v2 = fmaxf(__fadd_rn(__fmul_rn(acc[mt][nt][2], s), bb), 0.0f);
            float v3 = fmaxf(__fadd_rn(__fmul_rn(acc[mt][nt][3], s), bb), 0.0f);
            mx = fmaxf(mx, fmaxf(fmaxf(v0, v1), fmaxf(v2, v3)));
            base0[o]       = v0;
            base0[o + 128] = v1;
            base0[o + 256] = v2;
            base0[o + 384] = v3;
        }
    }
    mx = waveReduceMax(mx);
    if (lane == 0) wred[wv] = mx;
    __syncthreads();
    if (t == 0) {
        float m = fmaxf(fmaxf(wred[0], wred[1]), fmaxf(wred[2], wred[3]));
        slotAtomicMax(ws, 2, blockIdx.x & (NSLOT - 1), m);
    }
}

__global__ __launch_bounds__(256) void conv2_kernel(float* __restrict__ ws) {
    __shared__ unsigned short xt[4 * 58 * 40];
    __shared__ unsigned short wt[9 * 32 * 40];
    __shared__ float wred[4];
    const float* x2f = (const float*)((char*)ws + X2F_BYTE);
    const unsigned short* w2b = (const unsigned short*)(ws + OFF_W2B);
    const float* sc2 = ws + OFF_SC2;
    float* x3 = (float*)((char*)ws + X3_BYTE);
    int b = blockIdx.x / 28, hg = blockIdx.x % 28;
    int t = threadIdx.x, lane = t & 63, wv = t >> 6;
    int quad = lane >> 4, l16 = lane & 15;
    int r = wv >> 1;
    int h = hg * 2 + r;
    int wq = wv & 1;
    int w0 = wq * 24;
    float s_a2 = slotMax(ws, 2) / 127.0f + 1e-8f;
    float rinv = 1.0f / s_a2;
    const float* src = x2f + (size_t)(b * 58 + hg * 2) * 64 * 128;

    f32x4 acc[2][2];
    #pragma unroll
    for (int i = 0; i < 2; i++) { acc[i][0] = (f32x4){0.f,0.f,0.f,0.f}; acc[i][1] = (f32x4){0.f,0.f,0.f,0.f}; }

    for (int cs = 0; cs < 4; cs++) {
        __syncthreads();
        for (int s = t; s < 1152; s += 256) {
            int gi = s >> 2, q = s & 3;
            *(uint4*)&wt[gi * 40 + q * 8] = *(const uint4*)(w2b + gi * 128 + cs * 32 + q * 8);
        }
        #pragma unroll
        for (int k = 0; k < 8; k++) {
            int idx = t + k * 256;
            if (idx < 1856) {
                int row = idx / 464;
                int rem = idx - row * 464;
                int slot = rem >> 3, c4 = rem & 7;
                f32x4 v = *(const f32x4*)(src + (size_t)(row * 64 + slot) * 128 + cs * 32 + c4 * 4);
                unsigned q0 = bf16u(clamp8(rintf(v[0] * rinv)));
                unsigned q1 = bf16u(clamp8(rintf(v[1] * rinv)));
                unsigned q2 = bf16u(clamp8(rintf(v[2] * rinv)));
                unsigned q3 = bf16u(clamp8(rintf(v[3] * rinv)));
                uint2 pk; pk.x = q0 | (q1 << 16); pk.y = q2 | (q3 << 16);
                *(uint2*)&xt[(row * 58 + slot) * 40 + c4 * 4] = pk;
            }
        }
        __syncthreads();
        #pragma unroll
        for (int tap = 0; tap < 9; tap++) {
            int dh = tap / 3, dw = tap % 3;
            bf16x8 b0 = *(const bf16x8*)&wt[(tap * 32 + l16) * 40 + quad * 8];
            bf16x8 b1 = *(const bf16x8*)&wt[(tap * 32 + 16 + l16) * 40 + quad * 8];
            #pragma unroll
            for (int mt = 0; mt < 2; mt++) {
                int slot = w0 + mt * 16 + l16 + dw;
                bf16x8 a = *(const bf16x8*)&xt[((r + dh) * 58 + slot) * 40 + quad * 8];
                acc[mt][0] = __builtin_amdgcn_mfma_f32_16x16x32_bf16(a, b0, acc[mt][0], 0, 0, 0);
                acc[mt][1] = __builtin_amdgcn_mfma_f32_16x16x32_bf16(a, b1, acc[mt][1], 0, 0, 0);
            }
        }
    }
    float mx = 0.0f;
    #pragma unroll
    for (int nt = 0; nt < 2; nt++) {
        int g = nt * 16 + l16;
        float s2 = __fmul_rn(s_a2, sc2[g]);
        #pragma unroll
        for (int mt = 0; mt < 2; mt++) {
            int wb = w0 + mt * 16 + quad * 4;
            if (wq == 0 || wb >= 32) {
                float4 v;
                v.x = __fmul_rn(acc[mt][nt][0], s2);
                v.y = __fmul_rn(acc[mt][nt][1], s2);
                v.z = __fmul_rn(acc[mt][nt][2], s2);
                v.w = __fmul_rn(acc[mt][nt][3], s2);
                mx = fmaxf(mx, fmaxf(fmaxf(fabsf(v.x), fabsf(v.y)), fmaxf(fabsf(v.z), fabsf(v.w))));
                *(float4*)&x3[(size_t)(b * GRW + g) * HW + h * 56 + wb] = v;
            }
        }
    }
    mx = waveReduceMax(mx);
    if (lane == 0) wred[wv] = mx;
    __syncthreads();
    if (t == 0) {
        float m = fmaxf(fmaxf(wred[0], wred[1]), fmaxf(wred[2], wred[3]));
        slotAtomicMax(ws, 3, blockIdx.x & (NSLOT - 1), m);
    }
}

__global__ __launch_bounds__(256) void outq_kernel(const float4* __restrict__ batch4,
                                                   const float* __restrict__ ws,
                                                   float* __restrict__ out) {
    const float4* x34 = (const float4*)((const char*)ws + X3_BYTE);
    float maxb = slotMax(ws, 1);
    float max3 = slotMax(ws, 3);
    float s_out = fmaxf(maxb, max3) / 127.0f + 1e-8f;
    float4* out4 = (float4*)out;
    int n4 = NOUT / 4;
    for (int i = blockIdx.x * blockDim.x + threadIdx.x; i < n4; i += gridDim.x * blockDim.x) {
        int chl = i / 784;
        int b = chl / COUT;
        int ch = chl - b * COUT;
        int hw4 = i - chl * 784;
        float4 v;
        if (ch < CIN) v = batch4[(b * CIN + ch) * 784 + hw4];
        else          v = x34[(b * GRW + (ch - CIN)) * 784 + hw4];
        float4 r;
        r.x = __fmul_rn(clamp8(rintf(v.x / s_out)), s_out);
        r.y = __fmul_rn(clamp8(rintf(v.y / s_out)), s_out);
        r.z = __fmul_rn(clamp8(rintf(v.z / s_out)), s_out);
        r.w = __fmul_rn(clamp8(rintf(v.w / s_out)), s_out);
        out4[i] = r;
    }
    if (blockIdx.x == 0 && threadIdx.x == 0) out[NOUT] = s_out;
}

extern "C" void kernel_launch(void* const* d_in, const int* in_sizes, int n_in,
                              void* d_out, int out_size, void* d_ws, size_t ws_size,
                              hipStream_t stream) {
    const float4* batch = (const float4*)d_in[0];
    const float* s_in  = (const float*)d_in[1];
    const float* g1    = (const float*)d_in[2];
    const float* b1    = (const float*)d_in[3];
    const float* m1    = (const float*)d_in[4];
    const float* v1    = (const float*)d_in[5];
    const float* c1w   = (const float*)d_in[6];
    const float* g2    = (const float*)d_in[7];
    const float* b2    = (const float*)d_in[8];
    const float* m2    = (const float*)d_in[9];
    const float* v2    = (const float*)d_in[10];
    const float* c2w   = (const float*)d_in[11];
    float* out = (float*)d_out;
    float* ws  = (float*)d_ws;

    void* args[] = {(void*)&batch, (void*)&s_in, (void*)&g1, (void*)&b1, (void*)&m1,
                    (void*)&v1, (void*)&c1w, (void*)&g2, (void*)&b2, (void*)&m2,
                    (void*)&v2, (void*)&c2w, (void*)&ws, (void*)&out};
    hipError_t err = hipLaunchCooperativeKernel((const void*)fused_kernel, dim3(512), dim3(256),
                                                args, 0, stream);
    if (err != hipSuccess) {
        (void)hipGetLastError();
        err = hipLaunchCooperativeKernel((const void*)fused_kernel, dim3(256), dim3(256),
                                         args, 0, stream);
    }
    if (err != hipSuccess) {
        (void)hipGetLastError();
        // fallback: proven multi-kernel pipeline (R7 semantics for SC1/BFQ)
        hipLaunchKernelGGL(prep_kernel, dim3(33), dim3(256), 0, stream, g1, b1, m1, v1, s_in, ws);
        hipLaunchKernelGGL(max1_kernel, dim3(512), dim3(256), 0, stream, (const float4*)batch, ws);
        hipLaunchKernelGGL(prep2_kernel, dim3(160), dim3(256), 0, stream, c1w, g2, b2, m2, v2, c2w, ws);
        hipLaunchKernelGGL(conv1_kernel, dim3(32 * 49), dim3(256), 0, stream, (const float4*)batch, ws);
        hipLaunchKernelGGL(conv2_kernel, dim3(32 * 28), dim3(256), 0, stream, ws);
        hipLaunchKernelGGL(outq_kernel, dim3(4096), dim3(256), 0, stream, (const float4*)batch, ws, out);
    }
}

// Round 10
// 328.211 us; speedup vs baseline: 1.7938x; 1.7938x over previous
//
#include <hip/hip_runtime.h>

typedef __attribute__((ext_vector_type(8))) short bf16x8;
typedef __attribute__((ext_vector_type(4))) float f32x4;

// ---------------- problem constants ----------------
constexpr int B_   = 32;
constexpr int CIN  = 256;
constexpr int HW   = 56 * 56;      // 3136
constexpr int BOT  = 128;
constexpr int GRW  = 32;
constexpr int COUT = CIN + GRW;    // 288
constexpr int NBATCH = B_ * CIN * HW;   // 25,690,112
constexpr int NOUT   = B_ * COUT * HW;  // 28,901,376

// ---------------- workspace layout (float units unless noted) ----------------
// array 0 = max_x1, 1 = max|batch|, 2 = max_x2, 3 = max|x3|
constexpr int NSLOT = 32;
constexpr int SSTR  = 32;                         // 32 floats = 128 B stride
constexpr int OFF_SLOT = 16;
constexpr int OFF_W1Q  = OFF_SLOT + 4 * NSLOT * SSTR;
constexpr int OFF_B1Q  = OFF_W1Q + 256;
constexpr int OFF_BFQ  = OFF_B1Q + 256;          // 128 floats
constexpr int OFF_SC1  = OFF_BFQ + 128;          // 128 floats  (s_a1*s_w1[o])
constexpr int OFF_SC2  = OFF_SC1 + 128;          // 32 floats   (s_w2[g])
constexpr int OFF_WQ1B = OFF_SC2 + 32;           // ushort[128*256] = 16384 floats
constexpr int OFF_W2B  = OFF_WQ1B + 16384;       // ushort[9*32*128] = 18432 floats
constexpr int OFF_END  = OFF_W2B + 18432;
constexpr size_t X1Q_BYTE = (size_t)OFF_END * 4;          // int8 x1q [b][hw][c]        (25.7 MB)
constexpr size_t X2F_BYTE = X1Q_BYTE + (size_t)NBATCH;    // fp32 x2 padded CL [b][58][64][128] (60.8 MB)
constexpr size_t X2F_FLTS = (size_t)B_ * 58 * 64 * 128;
constexpr size_t X3_BYTE  = X2F_BYTE + X2F_FLTS * 4;      // fp32 x3 [b][g][hw]         (12.8 MB)

__device__ __forceinline__ void slotAtomicMax(float* ws, int a, int s, float v) {
    atomicMax((unsigned*)ws + OFF_SLOT + a * NSLOT * SSTR + s * SSTR, __float_as_uint(v));
}
__device__ __forceinline__ float slotMax(const float* ws, int a) {
    float m = 0.0f;
    #pragma unroll
    for (int s = 0; s < NSLOT; s++)
        m = fmaxf(m, ws[OFF_SLOT + a * NSLOT * SSTR + s * SSTR]);
    return m;
}

__device__ __forceinline__ float blockReduceMax256(float v) {
    #pragma unroll
    for (int o = 32; o > 0; o >>= 1) v = fmaxf(v, __shfl_down(v, o, 64));
    __shared__ float sm[4];
    if ((threadIdx.x & 63) == 0) sm[threadIdx.x >> 6] = v;
    __syncthreads();
    return fmaxf(fmaxf(sm[0], sm[1]), fmaxf(sm[2], sm[3]));
}
__device__ __forceinline__ float waveReduceMax(float v) {
    #pragma unroll
    for (int o = 32; o > 0; o >>= 1) v = fmaxf(v, __shfl_down(v, o, 64));
    return v;
}
__device__ __forceinline__ float clamp8(float r)   { return fminf(fmaxf(r, -128.0f), 127.0f); }
__device__ __forceinline__ float clampBig(float r) { return fminf(fmaxf(r, -2147483648.0f), 2147483648.0f); }
__device__ __forceinline__ unsigned short bf16u(float f) { return (unsigned short)(__float_as_uint(f) >> 16); }

// ---------------- prep: block 0 = scalars + BN1 folded weights; blocks 1..32 = x2f halo zero ----
__global__ __launch_bounds__(256) void prep_kernel(const float* __restrict__ g1, const float* __restrict__ b1p,
                                                   const float* __restrict__ m1, const float* __restrict__ v1,
                                                   const float* __restrict__ s_in_p, float* __restrict__ ws) {
    int t = threadIdx.x;
    if (blockIdx.x == 0) {
        int c = t;
        unsigned* scal = (unsigned*)ws;
        for (int s = c; s < OFF_W1Q; s += 256) scal[s] = 0u;
        float s_in = *s_in_p;
        float r = 1.0f / sqrtf(v1[c] + 1e-5f);
        float w1 = __fmul_rn(g1[c], r);
        float b1 = __fsub_rn(b1p[c], __fmul_rn(m1[c], w1));
        float mx = blockReduceMax256(fabsf(w1));
        float s_bn = mx / 127.0f + 1e-8f;
        ws[OFF_W1Q + c] = __fmul_rn(clamp8(rintf(w1 / s_bn)), s_bn);
        float sb = __fmul_rn(s_in, s_bn);
        ws[OFF_B1Q + c] = __fmul_rn(clampBig(rintf(b1 / sb)), sb);
        return;
    }
    // halo zeroing for batch image b
    int b = blockIdx.x - 1;
    float4* x2f4 = (float4*)((char*)ws + X2F_BYTE);
    float4 z; z.x = z.y = z.z = z.w = 0.0f;
    // row pads: hp in {0,57}, slots 0..57, 32 float4 each
    for (int i = t; i < 2 * 58 * 32; i += 256) {
        int row  = i / (58 * 32);
        int rest = i - row * (58 * 32);
        int slot = rest >> 5, q = rest & 31;
        int hp = row ? 57 : 0;
        x2f4[(((size_t)(b * 58 + hp) * 64 + slot) * 128 >> 2) + q] = z;
    }
    // col pads: hp 1..56, slots {0,57}
    for (int i = t; i < 56 * 2 * 32; i += 256) {
        int hp   = 1 + (i >> 6);
        int rest = i & 63;
        int slot = (rest >> 5) ? 57 : 0;
        int q = rest & 31;
        x2f4[(((size_t)(b * 58 + hp) * 64 + slot) * 128 >> 2) + q] = z;
    }
}

// ---------------- pass 1: max of relu(bn1(batch)) and max|batch| ----------------
__global__ __launch_bounds__(256) void max1_kernel(const float4* __restrict__ batch4,
                                                   float* __restrict__ ws) {
    const float* w1q = ws + OFF_W1Q;
    const float* b1q = ws + OFF_B1Q;
    int tid = blockIdx.x * 256 + threadIdx.x;      // 0..131071
    int row = tid >> 4;                            // 0..8191 = b*256 + c
    int f   = tid & 15;
    int c   = row & 255;
    float w = w1q[c], b = b1q[c];
    const float4* p = batch4 + (size_t)row * 784 + f;
    float mx1 = 0.0f, mxb = 0.0f;
    #pragma unroll 7
    for (int k = 0; k < 49; k++) {
        float4 v = p[k * 16];
        float x0 = fmaxf(__fadd_rn(__fmul_rn(v.x, w), b), 0.0f);
        float x1 = fmaxf(__fadd_rn(__fmul_rn(v.y, w), b), 0.0f);
        float x2 = fmaxf(__fadd_rn(__fmul_rn(v.z, w), b), 0.0f);
        float x3 = fmaxf(__fadd_rn(__fmul_rn(v.w, w), b), 0.0f);
        mx1 = fmaxf(mx1, fmaxf(fmaxf(x0, x1), fmaxf(x2, x3)));
        mxb = fmaxf(mxb, fmaxf(fmaxf(fabsf(v.x), fabsf(v.y)), fmaxf(fabsf(v.z), fabsf(v.w))));
    }
    mx1 = blockReduceMax256(mx1);
    __syncthreads();
    mxb = blockReduceMax256(mxb);
    if (threadIdx.x == 0) {
        int s = blockIdx.x & (NSLOT - 1);
        slotAtomicMax(ws, 0, s, mx1);
        slotAtomicMax(ws, 1, s, mxb);
    }
}

// ---------------- quantize x1 -> int8 in TRANSPOSED layout [b][hw][c] ----------------
// LDS row padded to 17 uints (68 B): breaks the (c*16 % 32 == 0) bank aliasing of the
// byte-gather phase (was 4-way; now <=2-way = free).
__global__ __launch_bounds__(256) void quant1_kernel(const float4* __restrict__ batch4,
                                                     float* __restrict__ ws) {
    __shared__ unsigned ldsq[256 * 17];   // [c][hw4 packed uchar4], stride 17
    const float* w1q = ws + OFF_W1Q;
    const float* b1q = ws + OFF_B1Q;
    float s_a1 = slotMax(ws, 0) / 127.0f + 1e-8f;
    int b = blockIdx.x / 49, hw0 = (blockIdx.x % 49) * 64;
    int t = threadIdx.x;
    int f = t & 15, cb = t >> 4;
    #pragma unroll
    for (int j = 0; j < 16; j++) {
        int c = cb + j * 16;
        float w = w1q[c], bb = b1q[c];
        float4 v = batch4[(b * 256 + c) * 784 + (hw0 >> 2) + f];
        unsigned q0 = (unsigned)(int)clamp8(rintf(fmaxf(__fadd_rn(__fmul_rn(v.x, w), bb), 0.0f) / s_a1));
        unsigned q1 = (unsigned)(int)clamp8(rintf(fmaxf(__fadd_rn(__fmul_rn(v.y, w), bb), 0.0f) / s_a1));
        unsigned q2 = (unsigned)(int)clamp8(rintf(fmaxf(__fadd_rn(__fmul_rn(v.z, w), bb), 0.0f) / s_a1));
        unsigned q3 = (unsigned)(int)clamp8(rintf(fmaxf(__fadd_rn(__fmul_rn(v.w, w), bb), 0.0f) / s_a1));
        ldsq[c * 17 + f] = q0 | (q1 << 8) | (q2 << 16) | (q3 << 24);
    }
    __syncthreads();
    const unsigned char* l8 = (const unsigned char*)ldsq;
    uint4* outv = (uint4*)((char*)ws + X1Q_BYTE);
    int hwl = t >> 2, cq = (t & 3) * 16;
    #pragma unroll
    for (int k = 0; k < 4; k++) {
        int c0 = cq + k * 64;
        unsigned u[4] = {0u, 0u, 0u, 0u};
        #pragma unroll
        for (int i = 0; i < 16; i++) {
            unsigned by = l8[(c0 + i) * 68 + hwl];
            u[i >> 2] |= by << ((i & 3) * 8);
        }
        uint4 val; val.x = u[0]; val.y = u[1]; val.z = u[2]; val.w = u[3];
        outv[(((size_t)b * 3136 + hw0 + hwl) * 256 + c0) >> 4] = val;
    }
}

// ---------------- prep2: fold bn2 -> int bf16 weights + scales ----------------
__global__ void prep2_kernel(const float* __restrict__ c1w,
                             const float* __restrict__ g2, const float* __restrict__ b2,
                             const float* __restrict__ m2, const float* __restrict__ v2,
                             const float* __restrict__ c2w, float* __restrict__ ws) {
    int bi = blockIdx.x;
    int t = threadIdx.x;
    unsigned short* wq1b = (unsigned short*)(ws + OFF_WQ1B);
    unsigned short* w2b  = (unsigned short*)(ws + OFF_W2B);
    if (bi < BOT) {
        int o = bi;
        float tt = __fmul_rn(g2[o], 1.0f / sqrtf(v2[o] + 1e-5f));
        float wf = __fmul_rn(c1w[o * CIN + t], tt);
        float mx = blockReduceMax256(fabsf(wf));
        float s_w1 = mx / 127.0f + 1e-8f;
        float m = clamp8(rintf(wf / s_w1));
        wq1b[o * CIN + t] = bf16u(m);
        if (t == 0) {
            float s_a1 = slotMax(ws, 0) / 127.0f + 1e-8f;
            ws[OFF_SC1 + o] = __fmul_rn(s_a1, s_w1);
            float bf = __fsub_rn(b2[o], __fmul_rn(m2[o], tt));
            float sb = __fmul_rn(s_a1, s_w1);
            ws[OFF_BFQ + o] = __fmul_rn(clampBig(rintf(bf / sb)), sb);
        }
    } else {
        int g = bi - BOT;
        float mx = 0.0f;
        for (int s = t; s < BOT * 9; s += 256) mx = fmaxf(mx, fabsf(c2w[g * BOT * 9 + s]));
        mx = blockReduceMax256(mx);
        float s_w2 = mx / 127.0f + 1e-8f;
        for (int s = t; s < BOT * 9; s += 256) {
            int c = s / 9, tap = s - c * 9;
            float m = clamp8(rintf(c2w[g * BOT * 9 + s] / s_w2));
            w2b[(tap * GRW + g) * BOT + c] = bf16u(m);
        }
        if (t == 0) ws[OFF_SC2 + g] = s_w2;
    }
}

// ---------------- conv1: 1x1 via bf16 MFMA from int8 x1q; epilogue -> padded CL fp32 ----------------
__global__ __launch_bounds__(256) void conv1_kernel(float* __restrict__ ws) {
    __shared__ unsigned short lA[64 * 136];
    __shared__ unsigned short lW[128 * 136];
    __shared__ float wred[4];
    const unsigned char* x1q = (const unsigned char*)((char*)ws + X1Q_BYTE);
    const unsigned short* wq1b = (const unsigned short*)(ws + OFF_WQ1B);
    const float* sc1 = ws + OFF_SC1;
    const float* bfq = ws + OFF_BFQ;
    float* x2f = (float*)((char*)ws + X2F_BYTE);
    int b = blockIdx.x / 49, hw0 = (blockIdx.x % 49) * 64;
    int t = threadIdx.x, lane = t & 63, wv = t >> 6;
    int quad = lane >> 4, l16 = lane & 15;
    int mhalf = wv & 1, nhalf = wv >> 1;
    f32x4 acc[2][4];
    #pragma unroll
    for (int i = 0; i < 2; i++)
        #pragma unroll
        for (int j = 0; j < 4; j++) acc[i][j] = (f32x4){0.f, 0.f, 0.f, 0.f};

    for (int kc = 0; kc < 256; kc += 128) {
        __syncthreads();
        {   // stage A: 64 hw x 128 c, int8 -> int-valued bf16
            int cb = t & 7, hwi = t >> 3;
            #pragma unroll
            for (int r = 0; r < 2; r++) {
                int hw = hwi + r * 32;
                uint4 p = *(const uint4*)(x1q + ((size_t)b * 3136 + hw0 + hw) * 256 + kc + cb * 16);
                unsigned wd[4] = {p.x, p.y, p.z, p.w};
                bf16x8 t0, t1;
                #pragma unroll
                for (int j = 0; j < 8; j++)
                    t0[j] = (short)bf16u((float)((wd[j >> 2] >> ((j & 3) * 8)) & 255u));
                #pragma unroll
                for (int j = 0; j < 8; j++)
                    t1[j] = (short)bf16u((float)((wd[2 + (j >> 2)] >> ((j & 3) * 8)) & 255u));
                *(bf16x8*)&lA[hw * 136 + cb * 16] = t0;
                *(bf16x8*)&lA[hw * 136 + cb * 16 + 8] = t1;
            }
        }
        {   // stage W: 128 o x 128 c
            int cb = t & 7, oi = t >> 3;
            #pragma unroll
            for (int r = 0; r < 4; r++) {
                int o = oi + r * 32;
                uint4 p0 = *(const uint4*)(wq1b + o * 256 + kc + cb * 16);
                uint4 p1 = *(const uint4*)(wq1b + o * 256 + kc + cb * 16 + 8);
                *(uint4*)&lW[o * 136 + cb * 16] = p0;
                *(uint4*)&lW[o * 136 + cb * 16 + 8] = p1;
            }
        }
        __syncthreads();
        #pragma unroll
        for (int ks = 0; ks < 4; ks++) {
            bf16x8 a0 = *(const bf16x8*)&lA[(mhalf * 32 + l16) * 136 + ks * 32 + quad * 8];
            bf16x8 a1 = *(const bf16x8*)&lA[(mhalf * 32 + 16 + l16) * 136 + ks * 32 + quad * 8];
            #pragma unroll
            for (int nt = 0; nt < 4; nt++) {
                bf16x8 bfr = *(const bf16x8*)&lW[(nhalf * 64 + nt * 16 + l16) * 136 + ks * 32 + quad * 8];
                acc[0][nt] = __builtin_amdgcn_mfma_f32_16x16x32_bf16(a0, bfr, acc[0][nt], 0, 0, 0);
                acc[1][nt] = __builtin_amdgcn_mfma_f32_16x16x32_bf16(a1, bfr, acc[1][nt], 0, 0, 0);
            }
        }
    }
    float mx = 0.0f;
    #pragma unroll
    for (int mt = 0; mt < 2; mt++) {
        int hwg = hw0 + mhalf * 32 + mt * 16 + quad * 4;   // multiple of 4; 4-group never crosses a row
        int h = (int)(((unsigned)hwg * 9363u) >> 19);      // exact /56 for 0..3135
        int w = hwg - h * 56;
        float* base0 = x2f + ((size_t)(b * 58 + h + 1) * 64 + (w + 1)) * 128;
        #pragma unroll
        for (int nt = 0; nt < 4; nt++) {
            int o = nhalf * 64 + nt * 16 + l16;
            float s = sc1[o], bb = bfq[o];
            float v0 = fmaxf(__fadd_rn(__fmul_rn(acc[mt][nt][0], s), bb), 0.0f);
            float v1 = fmaxf(__fadd_rn(__fmul_rn(acc[mt][nt][1], s), bb), 0.0f);
            float v2 = fmaxf(__fadd_rn(__fmul_rn(acc[mt][nt][2], s), bb), 0.0f);
            float v3 = fmaxf(__fadd_rn(__fmul_rn(acc[mt][nt][3], s), bb), 0.0f);
            mx = fmaxf(mx, fmaxf(fmaxf(v0, v1), fmaxf(v2, v3)));
            base0[o]       = v0;
            base0[o + 128] = v1;
            base0[o + 256] = v2;
            base0[o + 384] = v3;
        }
    }
    mx = waveReduceMax(mx);
    if (lane == 0) wred[wv] = mx;
    __syncthreads();
    if (t == 0) {
        float m = fmaxf(fmaxf(wred[0], wred[1]), fmaxf(wred[2], wred[3]));
        slotAtomicMax(ws, 2, blockIdx.x & (NSLOT - 1), m);
    }
}

// ---------------- conv2: 3x3; stage x-tile to LDS with quantize-on-stage; MFMA from LDS ----
__global__ __launch_bounds__(256) void conv2_kernel(float* __restrict__ ws) {
    __shared__ unsigned short xt[4 * 58 * 40];   // [row][slot][c40] bf16 ints, 18.6 KB
    __shared__ unsigned short wt[9 * 32 * 40];   // [tap*32+g][c40], 23 KB
    __shared__ float wred[4];
    const float* x2f = (const float*)((char*)ws + X2F_BYTE);
    const unsigned short* w2b = (const unsigned short*)(ws + OFF_W2B);
    const float* sc2 = ws + OFF_SC2;
    float* x3 = (float*)((char*)ws + X3_BYTE);
    int b = blockIdx.x / 28, hg = blockIdx.x % 28;
    int t = threadIdx.x, lane = t & 63, wv = t >> 6;
    int quad = lane >> 4, l16 = lane & 15;
    int r = wv >> 1;                     // output row within block (0/1)
    int h = hg * 2 + r;                  // output row 0..55
    int wq = wv & 1;
    int w0 = wq * 24;                    // w-halves 0..31 and 24..55 (overlap masked on store)
    float s_a2 = slotMax(ws, 2) / 127.0f + 1e-8f;
    float rinv = 1.0f / s_a2;
    const float* src = x2f + (size_t)(b * 58 + hg * 2) * 64 * 128;   // 4 padded rows

    f32x4 acc[2][2];
    #pragma unroll
    for (int i = 0; i < 2; i++) { acc[i][0] = (f32x4){0.f,0.f,0.f,0.f}; acc[i][1] = (f32x4){0.f,0.f,0.f,0.f}; }

    for (int cs = 0; cs < 4; cs++) {
        __syncthreads();
        // stage weights for this c-slice
        for (int s = t; s < 1152; s += 256) {
            int gi = s >> 2, q = s & 3;
            *(uint4*)&wt[gi * 40 + q * 8] = *(const uint4*)(w2b + gi * 128 + cs * 32 + q * 8);
        }
        // stage x-tile: 4 rows x 58 slots x 32 c, quantize once per element
        #pragma unroll
        for (int k = 0; k < 8; k++) {
            int idx = t + k * 256;                 // 0..1855 (4*58*8)
            if (idx < 1856) {
                int row = idx / 464;
                int rem = idx - row * 464;
                int slot = rem >> 3, c4 = rem & 7;
                f32x4 v = *(const f32x4*)(src + (size_t)(row * 64 + slot) * 128 + cs * 32 + c4 * 4);
                unsigned q0 = bf16u(clamp8(rintf(v[0] * rinv)));
                unsigned q1 = bf16u(clamp8(rintf(v[1] * rinv)));
                unsigned q2 = bf16u(clamp8(rintf(v[2] * rinv)));
                unsigned q3 = bf16u(clamp8(rintf(v[3] * rinv)));
                uint2 pk; pk.x = q0 | (q1 << 16); pk.y = q2 | (q3 << 16);
                *(uint2*)&xt[(row * 58 + slot) * 40 + c4 * 4] = pk;
            }
        }
        __syncthreads();
        #pragma unroll
        for (int tap = 0; tap < 9; tap++) {
            int dh = tap / 3, dw = tap % 3;
            bf16x8 b0 = *(const bf16x8*)&wt[(tap * 32 + l16) * 40 + quad * 8];
            bf16x8 b1 = *(const bf16x8*)&wt[(tap * 32 + 16 + l16) * 40 + quad * 8];
            #pragma unroll
            for (int mt = 0; mt < 2; mt++) {
                int slot = w0 + mt * 16 + l16 + dw;
                bf16x8 a = *(const bf16x8*)&xt[((r + dh) * 58 + slot) * 40 + quad * 8];
                acc[mt][0] = __builtin_amdgcn_mfma_f32_16x16x32_bf16(a, b0, acc[mt][0], 0, 0, 0);
                acc[mt][1] = __builtin_amdgcn_mfma_f32_16x16x32_bf16(a, b1, acc[mt][1], 0, 0, 0);
            }
        }
    }
    float mx = 0.0f;
    #pragma unroll
    for (int nt = 0; nt < 2; nt++) {
        int g = nt * 16 + l16;
        float s2 = __fmul_rn(s_a2, sc2[g]);
        #pragma unroll
        for (int mt = 0; mt < 2; mt++) {
            int wb = w0 + mt * 16 + quad * 4;
            if (wq == 0 || wb >= 32) {
                float4 v;
                v.x = __fmul_rn(acc[mt][nt][0], s2);
                v.y = __fmul_rn(acc[mt][nt][1], s2);
                v.z = __fmul_rn(acc[mt][nt][2], s2);
                v.w = __fmul_rn(acc[mt][nt][3], s2);
                mx = fmaxf(mx, fmaxf(fmaxf(fabsf(v.x), fabsf(v.y)), fmaxf(fabsf(v.z), fabsf(v.w))));
                *(float4*)&x3[(size_t)(b * GRW + g) * HW + h * 56 + wb] = v;
            }
        }
    }
    mx = waveReduceMax(mx);
    if (lane == 0) wred[wv] = mx;
    __syncthreads();
    if (t == 0) {
        float m = fmaxf(fmaxf(wred[0], wred[1]), fmaxf(wred[2], wred[3]));
        slotAtomicMax(ws, 3, blockIdx.x & (NSLOT - 1), m);
    }
}

// ---------------- output: concat + fake-quant ----------------
__global__ __launch_bounds__(256) void outq_kernel(const float4* __restrict__ batch4,
                                                   const float* __restrict__ ws,
                                                   float* __restrict__ out) {
    const float4* x34 = (const float4*)((const char*)ws + X3_BYTE);
    float maxb = slotMax(ws, 1);
    float max3 = slotMax(ws, 3);
    float s_out = fmaxf(maxb, max3) / 127.0f + 1e-8f;
    float4* out4 = (float4*)out;
    int n4 = NOUT / 4;
    for (int i = blockIdx.x * blockDim.x + threadIdx.x; i < n4; i += gridDim.x * blockDim.x) {
        int chl = i / 784;
        int b = chl / COUT;
        int ch = chl - b * COUT;
        int hw4 = i - chl * 784;
        float4 v;
        if (ch < CIN) v = batch4[(b * CIN + ch) * 784 + hw4];
        else          v = x34[(b * GRW + (ch - CIN)) * 784 + hw4];
        float4 r;
        r.x = __fmul_rn(clamp8(rintf(v.x / s_out)), s_out);
        r.y = __fmul_rn(clamp8(rintf(v.y / s_out)), s_out);
        r.z = __fmul_rn(clamp8(rintf(v.z / s_out)), s_out);
        r.w = __fmul_rn(clamp8(rintf(v.w / s_out)), s_out);
        out4[i] = r;
    }
    if (blockIdx.x == 0 && threadIdx.x == 0) out[NOUT] = s_out;
}

extern "C" void kernel_launch(void* const* d_in, const int* in_sizes, int n_in,
                              void* d_out, int out_size, void* d_ws, size_t ws_size,
                              hipStream_t stream) {
    const float* batch = (const float*)d_in[0];
    const float* s_in  = (const float*)d_in[1];
    const float* g1    = (const float*)d_in[2];
    const float* b1    = (const float*)d_in[3];
    const float* m1    = (const float*)d_in[4];
    const float* v1    = (const float*)d_in[5];
    const float* c1w   = (const float*)d_in[6];
    const float* g2    = (const float*)d_in[7];
    const float* b2    = (const float*)d_in[8];
    const float* m2    = (const float*)d_in[9];
    const float* v2    = (const float*)d_in[10];
    const float* c2w   = (const float*)d_in[11];
    float* out = (float*)d_out;
    float* ws  = (float*)d_ws;

    hipLaunchKernelGGL(prep_kernel, dim3(33), dim3(256), 0, stream, g1, b1, m1, v1, s_in, ws);
    hipLaunchKernelGGL(max1_kernel, dim3(512), dim3(256), 0, stream, (const float4*)batch, ws);
    hipLaunchKernelGGL(quant1_kernel, dim3(32 * 49), dim3(256), 0, stream, (const float4*)batch, ws);
    hipLaunchKernelGGL(prep2_kernel, dim3(160), dim3(256), 0, stream, c1w, g2, b2, m2, v2, c2w, ws);
    hipLaunchKernelGGL(conv1_kernel, dim3(32 * 49), dim3(256), 0, stream, ws);
    hipLaunchKernelGGL(conv2_kernel, dim3(32 * 28), dim3(256), 0, stream, ws);
    hipLaunchKernelGGL(outq_kernel, dim3(4096), dim3(256), 0, stream, (const float4*)batch, ws, out);
}